// Round 2
// baseline (3801.498 us; speedup 1.0000x reference)
//
#include <hip/hip_runtime.h>
#include <math.h>

#define H_ 128
#define W_ 128
#define HW_ (128*128)

// ---------------- BN folding: scale = g*rsqrt(v+eps), shift = b - m*scale ----
__global__ void fold_bn_kernel(const float* __restrict__ g, const float* __restrict__ b,
                               const float* __restrict__ m, const float* __restrict__ v,
                               float* __restrict__ scale, float* __restrict__ shift, int n) {
  int i = blockIdx.x * blockDim.x + threadIdx.x;
  if (i < n) {
    float inv = rsqrtf(v[i] + 1e-5f);
    float s = g[i] * inv;
    scale[i] = s;
    shift[i] = b[i] - m[i] * s;
  }
}

// ---------------- Direct conv3x3 SAME, fused BN (+optional add of existing out, +optional ReLU)
// Block: 256 threads. Tile: 32(w) x 8(h) spatial, 16 output channels.
// Thread: tx=tid&7 (4 consecutive px along w), ty=(tid>>3)&7 (row), tz=tid>>6 (4 couts).
// Wave = all (tx,ty) for one tz -> weight LDS reads are wave-uniform broadcasts.
template<bool RELU, bool ADD_IN>
__global__ __launch_bounds__(256) void conv3x3_kernel(
    const float* __restrict__ in_, const float* __restrict__ wgt,
    const float* __restrict__ scale, const float* __restrict__ shift,
    float* __restrict__ out_, int Cin, int Cout)
{
  constexpr int TW = 32, TH = 8, TCO = 16, CIC = 8;
  __shared__ float s_in[CIC][TH + 2][35];   // 34 used cols, stride 35 (odd) -> <=2-way banks
  __shared__ float s_w[CIC][TCO][12];       // 9 used, pad 12 -> 16B-aligned float4 reads

  const int tid = threadIdx.x;
  const int tx = tid & 7;
  const int ty = (tid >> 3) & 7;
  const int tz = tid >> 6;

  const int w0  = (blockIdx.x & 3) * TW;
  const int h0  = (blockIdx.x >> 2) * TH;
  const int co0 = blockIdx.y * TCO;
  const int b   = blockIdx.z;

  const float* in  = in_  + (size_t)b * Cin  * HW_;
  float*       out = out_ + (size_t)b * Cout * HW_;

  float acc[4][4];
  #pragma unroll
  for (int i = 0; i < 4; i++)
    #pragma unroll
    for (int j = 0; j < 4; j++) acc[i][j] = 0.0f;

  const int cb = tx * 4;

  for (int ci0 = 0; ci0 < Cin; ci0 += CIC) {
    __syncthreads();
    // stage input tile (with SAME halo, zero-padded)
    for (int idx = tid; idx < CIC * (TH + 2) * 34; idx += 256) {
      int ci  = idx / 340;
      int rem = idx - ci * 340;
      int rr  = rem / 34;
      int cc  = rem - rr * 34;
      int gh = h0 + rr - 1;
      int gw = w0 + cc - 1;
      float v = 0.0f;
      if ((unsigned)gh < (unsigned)H_ && (unsigned)gw < (unsigned)W_)
        v = in[(size_t)(ci0 + ci) * HW_ + gh * W_ + gw];
      s_in[ci][rr][cc] = v;
    }
    // stage weights (OIHW)
    for (int idx = tid; idx < CIC * TCO * 9; idx += 256) {
      int ci  = idx / 144;
      int rem = idx - ci * 144;
      int co  = rem / 9;
      int k   = rem - co * 9;
      s_w[ci][co][k] = wgt[((size_t)(co0 + co) * Cin + (ci0 + ci)) * 9 + k];
    }
    __syncthreads();

    #pragma unroll
    for (int ci = 0; ci < CIC; ci++) {
      float r0[6], r1[6], r2[6];
      #pragma unroll
      for (int j = 0; j < 6; j++) {
        r0[j] = s_in[ci][ty + 0][cb + j];
        r1[j] = s_in[ci][ty + 1][cb + j];
        r2[j] = s_in[ci][ty + 2][cb + j];
      }
      #pragma unroll
      for (int co = 0; co < 4; co++) {
        const float* wp = &s_w[ci][tz * 4 + co][0];
        float4 wa = *(const float4*)wp;          // k0..k3
        float4 wb = *(const float4*)(wp + 4);    // k4..k7
        float  w8 = wp[8];                       // k8
        #pragma unroll
        for (int px = 0; px < 4; px++) {
          float s = acc[co][px];
          s = fmaf(wa.x, r0[px + 0], s);
          s = fmaf(wa.y, r0[px + 1], s);
          s = fmaf(wa.z, r0[px + 2], s);
          s = fmaf(wa.w, r1[px + 0], s);
          s = fmaf(wb.x, r1[px + 1], s);
          s = fmaf(wb.y, r1[px + 2], s);
          s = fmaf(wb.z, r2[px + 0], s);
          s = fmaf(wb.w, r2[px + 1], s);
          s = fmaf(w8,   r2[px + 2], s);
          acc[co][px] = s;
        }
      }
    }
  }

  const int gh = h0 + ty;
  #pragma unroll
  for (int co = 0; co < 4; co++) {
    int gco = co0 + tz * 4 + co;
    float sc = scale[gco];
    float sh = shift[gco];
    float* op = out + (size_t)gco * HW_ + gh * W_ + w0 + cb;
    float4 v;
    v.x = acc[co][0] * sc + sh;
    v.y = acc[co][1] * sc + sh;
    v.z = acc[co][2] * sc + sh;
    v.w = acc[co][3] * sc + sh;
    if (ADD_IN) {
      float4 o = *(const float4*)op;
      v.x += o.x; v.y += o.y; v.z += o.z; v.w += o.w;
    }
    if (RELU) {
      v.x = fmaxf(v.x, 0.0f); v.y = fmaxf(v.y, 0.0f);
      v.z = fmaxf(v.z, 0.0f); v.w = fmaxf(v.w, 0.0f);
    }
    *(float4*)op = v;
  }
}

// ---------------- conv1x1 + BN (no ReLU): 64px x 64co tile, thread = 4px x 4co
__global__ __launch_bounds__(256) void conv1x1_kernel(
    const float* __restrict__ in_, const float* __restrict__ wgt,
    const float* __restrict__ scale, const float* __restrict__ shift,
    float* __restrict__ out_, int Cin, int Cout)
{
  constexpr int CIC = 8;
  __shared__ float s_x[CIC][64];
  __shared__ float s_w[CIC][64];

  const int tid = threadIdx.x;
  const int tx = tid & 15;   // pixel group (4 px)
  const int tz = tid >> 4;   // cout group (4 co)
  const int p0  = blockIdx.x * 64;
  const int co0 = blockIdx.y * 64;
  const int b   = blockIdx.z;
  const float* in  = in_  + (size_t)b * Cin  * HW_;
  float*       out = out_ + (size_t)b * Cout * HW_;

  float acc[4][4];
  #pragma unroll
  for (int i = 0; i < 4; i++)
    #pragma unroll
    for (int j = 0; j < 4; j++) acc[i][j] = 0.0f;

  for (int ci0 = 0; ci0 < Cin; ci0 += CIC) {
    __syncthreads();
    for (int idx = tid; idx < CIC * 64; idx += 256) {
      int ci = idx >> 6, c = idx & 63;
      s_x[ci][c] = in[(size_t)(ci0 + ci) * HW_ + p0 + c];
      s_w[ci][c] = wgt[(size_t)(co0 + c) * Cin + (ci0 + ci)];
    }
    __syncthreads();
    #pragma unroll
    for (int ci = 0; ci < CIC; ci++) {
      float4 xv = *(const float4*)&s_x[ci][tx * 4];
      float4 wv = *(const float4*)&s_w[ci][tz * 4];
      acc[0][0] = fmaf(wv.x, xv.x, acc[0][0]); acc[0][1] = fmaf(wv.x, xv.y, acc[0][1]);
      acc[0][2] = fmaf(wv.x, xv.z, acc[0][2]); acc[0][3] = fmaf(wv.x, xv.w, acc[0][3]);
      acc[1][0] = fmaf(wv.y, xv.x, acc[1][0]); acc[1][1] = fmaf(wv.y, xv.y, acc[1][1]);
      acc[1][2] = fmaf(wv.y, xv.z, acc[1][2]); acc[1][3] = fmaf(wv.y, xv.w, acc[1][3]);
      acc[2][0] = fmaf(wv.z, xv.x, acc[2][0]); acc[2][1] = fmaf(wv.z, xv.y, acc[2][1]);
      acc[2][2] = fmaf(wv.z, xv.z, acc[2][2]); acc[2][3] = fmaf(wv.z, xv.w, acc[2][3]);
      acc[3][0] = fmaf(wv.w, xv.x, acc[3][0]); acc[3][1] = fmaf(wv.w, xv.y, acc[3][1]);
      acc[3][2] = fmaf(wv.w, xv.z, acc[3][2]); acc[3][3] = fmaf(wv.w, xv.w, acc[3][3]);
    }
  }

  #pragma unroll
  for (int co = 0; co < 4; co++) {
    int gco = co0 + tz * 4 + co;
    float sc = scale[gco];
    float sh = shift[gco];
    float4 v;
    v.x = acc[co][0] * sc + sh;
    v.y = acc[co][1] * sc + sh;
    v.z = acc[co][2] * sc + sh;
    v.w = acc[co][3] * sc + sh;
    *(float4*)(out + (size_t)gco * HW_ + p0 + tx * 4) = v;
  }
}

// ---------------- reverse cummax over H, in place. block = 128 threads (one per w)
__global__ void colscan_kernel(float* __restrict__ p) {
  float* base = p + (size_t)blockIdx.x * HW_ + threadIdx.x;
  float m = -INFINITY;
  for (int g = 31; g >= 0; g--) {
    float v3 = base[(4 * g + 3) * W_];
    float v2 = base[(4 * g + 2) * W_];
    float v1 = base[(4 * g + 1) * W_];
    float v0 = base[(4 * g + 0) * W_];
    m = fmaxf(m, v3); base[(4 * g + 3) * W_] = m;
    m = fmaxf(m, v2); base[(4 * g + 2) * W_] = m;
    m = fmaxf(m, v1); base[(4 * g + 1) * W_] = m;
    m = fmaxf(m, v0); base[(4 * g + 0) * W_] = m;
  }
}

// ---------------- reverse cummax over W of p2 + add cp1 (in p1) -> write into p1 (=s)
__global__ void rowscan_add_kernel(const float* __restrict__ p2, float* __restrict__ p1) {
  __shared__ float buf[128];
  const int i = threadIdx.x;
  const size_t base = (size_t)blockIdx.x * W_;
  buf[i] = p2[base + i];
  __syncthreads();
  #pragma unroll
  for (int d = 1; d < 128; d <<= 1) {
    float v = buf[i];
    if (i + d < 128) v = fmaxf(v, buf[i + d]);
    __syncthreads();
    buf[i] = v;
    __syncthreads();
  }
  p1[base + i] = buf[i] + p1[base + i];
}

extern "C" void kernel_launch(void* const* d_in, const int* in_sizes, int n_in,
                              void* d_out, int out_size, void* d_ws, size_t ws_size,
                              hipStream_t stream) {
  const float* x    = (const float*)d_in[0];
  const float* w_p1 = (const float*)d_in[1];
  const float* g_p1 = (const float*)d_in[2];
  const float* b_p1 = (const float*)d_in[3];
  const float* m_p1 = (const float*)d_in[4];
  const float* v_p1 = (const float*)d_in[5];
  const float* w_p2 = (const float*)d_in[6];
  const float* g_p2 = (const float*)d_in[7];
  const float* b_p2 = (const float*)d_in[8];
  const float* m_p2 = (const float*)d_in[9];
  const float* v_p2 = (const float*)d_in[10];
  const float* w_c1 = (const float*)d_in[11];
  const float* g_c1 = (const float*)d_in[12];
  const float* b_c1 = (const float*)d_in[13];
  const float* m_c1 = (const float*)d_in[14];
  const float* v_c1 = (const float*)d_in[15];
  const float* w_c2 = (const float*)d_in[16];
  const float* g_c2 = (const float*)d_in[17];
  const float* b_c2 = (const float*)d_in[18];
  const float* m_c2 = (const float*)d_in[19];
  const float* v_c2 = (const float*)d_in[20];
  const float* w_p3 = (const float*)d_in[21];
  const float* g_p3 = (const float*)d_in[22];
  const float* b_p3 = (const float*)d_in[23];
  const float* m_p3 = (const float*)d_in[24];
  const float* v_p3 = (const float*)d_in[25];

  float* out = (float*)d_out;
  float* ws  = (float*)d_ws;

  // Workspace layout (floats). r overlays p2 (p2 dead after rowscan_add).
  float* p1 = ws;                         //  8,388,608  (4x128x128x128)
  float* p2 = ws + 8388608;               //  8,388,608
  float* r  = ws + 8388608;               // 16,777,216  (4x256x128x128) overlays p2
  float* prm = ws + 25165824;             //  2,048 params
  float* sc_p1 = prm + 0;    float* sh_p1 = prm + 128;
  float* sc_p2 = prm + 256;  float* sh_p2 = prm + 384;
  float* sc_c1 = prm + 512;  float* sh_c1 = prm + 768;
  float* sc_c2 = prm + 1024; float* sh_c2 = prm + 1280;
  float* sc_p3 = prm + 1536; float* sh_p3 = prm + 1792;

  fold_bn_kernel<<<1, 128, 0, stream>>>(g_p1, b_p1, m_p1, v_p1, sc_p1, sh_p1, 128);
  fold_bn_kernel<<<1, 128, 0, stream>>>(g_p2, b_p2, m_p2, v_p2, sc_p2, sh_p2, 128);
  fold_bn_kernel<<<1, 256, 0, stream>>>(g_c1, b_c1, m_c1, v_c1, sc_c1, sh_c1, 256);
  fold_bn_kernel<<<1, 256, 0, stream>>>(g_c2, b_c2, m_c2, v_c2, sc_c2, sh_c2, 256);
  fold_bn_kernel<<<1, 256, 0, stream>>>(g_p3, b_p3, m_p3, v_p3, sc_p3, sh_p3, 256);

  // p1 = relu(bn(conv3x3(x, w_p1))), p2 = relu(bn(conv3x3(x, w_p2)))   (256 -> 128)
  conv3x3_kernel<true, false><<<dim3(64, 8, 4), 256, 0, stream>>>(x, w_p1, sc_p1, sh_p1, p1, 256, 128);
  conv3x3_kernel<true, false><<<dim3(64, 8, 4), 256, 0, stream>>>(x, w_p2, sc_p2, sh_p2, p2, 256, 128);

  // corner pooling: cp1 (reverse cummax over H) in-place on p1; then s = rowscan(p2) + cp1 -> p1
  colscan_kernel<<<512, 128, 0, stream>>>(p1);
  rowscan_add_kernel<<<4 * 128 * 128, 128, 0, stream>>>(p2, p1);

  // bn2 = bn(conv1x1(x, w_c2)) -> r   (p2 region is dead now; r overlays it)
  conv1x1_kernel<<<dim3(256, 4, 4), 256, 0, stream>>>(x, w_c2, sc_c2, sh_c2, r, 256, 256);

  // r = relu(bn(conv3x3(s, w_c1)) + r)   (128 -> 256, ADD_IN, RELU)
  conv3x3_kernel<true, true><<<dim3(64, 16, 4), 256, 0, stream>>>(p1, w_c1, sc_c1, sh_c1, r, 128, 256);

  // out = relu(bn(conv3x3(r, w_p3)))   (256 -> 256)
  conv3x3_kernel<true, false><<<dim3(64, 16, 4), 256, 0, stream>>>(r, w_p3, sc_p3, sh_p3, out, 256, 256);
}

// Round 3
// 705.587 us; speedup vs baseline: 5.3877x; 5.3877x over previous
//
#include <hip/hip_runtime.h>
#include <math.h>

#define HH 128
#define WW 128
#define HWSZ (128*128)

typedef __attribute__((ext_vector_type(8))) short short8;
typedef __attribute__((ext_vector_type(4))) float float4v;

__device__ inline short f2bf(float f) {
  unsigned x = __float_as_uint(f);
  unsigned r = (x + 0x7fffu + ((x >> 16) & 1u)) >> 16;
  return (short)r;
}
__device__ inline float bf2f(unsigned short u) {
  return __uint_as_float(((unsigned)u) << 16);
}

// ---------------- BN folding ----------------
__global__ void fold_bn_kernel(const float* __restrict__ g, const float* __restrict__ b,
                               const float* __restrict__ m, const float* __restrict__ v,
                               float* __restrict__ scale, float* __restrict__ shift, int n) {
  int i = blockIdx.x * blockDim.x + threadIdx.x;
  if (i < n) {
    float inv = rsqrtf(v[i] + 1e-5f);
    float s = g[i] * inv;
    scale[i] = s;
    shift[i] = b[i] - m[i] * s;
  }
}

__global__ void add_shift_kernel(const float* __restrict__ a, const float* __restrict__ b,
                                 float* __restrict__ o) {
  int i = threadIdx.x;
  o[i] = a[i] + b[i];
}

// ---------------- weight convert: OIHW fp32 -> [tap][256 co][Cin] bf16, scale folded
__global__ void wcvt3_kernel(const float* __restrict__ w, const float* __restrict__ scale,
                             short* __restrict__ out, int Cin, int CoutW, int co_off) {
  int idx = blockIdx.x * blockDim.x + threadIdx.x;
  int total = CoutW * Cin * 9;
  if (idx >= total) return;
  int t  = idx % 9;
  int ci = (idx / 9) % Cin;
  int co = idx / (9 * Cin);
  out[((size_t)t * 256 + co_off + co) * Cin + ci] = f2bf(w[idx] * scale[co]);
}

// 1x1: [co][ci] fp32 -> [co][ci] bf16 scaled
__global__ void wcvt1_kernel(const float* __restrict__ w, const float* __restrict__ scale,
                             short* __restrict__ out, int Cin, int CoutW) {
  int idx = blockIdx.x * blockDim.x + threadIdx.x;
  if (idx >= CoutW * Cin) return;
  int co = idx / Cin;
  out[idx] = f2bf(w[idx] * scale[co]);
}

// ---------------- MFMA implicit-GEMM conv3x3 (+optional fused 1x1 phase) ----------------
// Block: 256 thr = 4 waves (2x2 wave grid). Tile: M=128 px (one row of one image) x N=128 co.
// grid.x = b*128 + h, grid.y = n-tile (2 -> couts 0..127 / 128..255).
// A LDS: [130 wpad][32 ci] bf16. B LDS: [3 dx][128 co][32 ci] bf16 (BN-scale prefolded).
template<bool SRC_F32, int CIN_A, int CIN_B, bool SPLIT_OUT, bool OUT_F32>
__global__ __launch_bounds__(256) void conv_mfma(
    const void* __restrict__ srcA, const float* __restrict__ xB,
    const short* __restrict__ wbA, const short* __restrict__ wbB,
    const float* __restrict__ shift,
    void* __restrict__ out0, void* __restrict__ out1)
{
  __shared__ short A_s[130 * 32];
  __shared__ short B_s[3 * 128 * 32];

  const int tid  = threadIdx.x;
  const int wave = tid >> 6;
  const int lane = tid & 63;
  const int wm = wave & 1;          // px half (0/1 -> 64)
  const int wn = wave >> 1;         // co half
  const int lr = lane & 15;
  const int lk = lane >> 4;

  const int h  = blockIdx.x & 127;
  const int b  = blockIdx.x >> 7;
  const int nt = blockIdx.y;
  const int co0 = nt * 128;

  float4v acc[4][4];
  #pragma unroll
  for (int i = 0; i < 4; i++)
    #pragma unroll
    for (int j = 0; j < 4; j++) acc[i][j] = (float4v)(0.0f);

  // ---------- phase A: 3x3 over srcA ----------
  for (int dy = 0; dy < 3; dy++) {
    int hh = h + dy - 1;
    if (hh < 0 || hh >= HH) continue;          // block-uniform
    for (int ci0 = 0; ci0 < CIN_A; ci0 += 32) {
      __syncthreads();
      // ---- stage A: [130][32]
      if (SRC_F32) {
        const float* src = (const float*)srcA + ((size_t)b * CIN_A + ci0) * HWSZ + (size_t)hh * WW;
        for (int idx = tid; idx < 16 * 130; idx += 256) {
          int cp = idx / 130;       // ci pair
          int wp = idx - cp * 130;  // wpad
          int w = wp - 1;
          float f0 = 0.0f, f1 = 0.0f;
          if ((unsigned)w < (unsigned)WW) {
            f0 = src[(size_t)(2 * cp) * HWSZ + w];
            f1 = src[(size_t)(2 * cp + 1) * HWSZ + w];
          }
          unsigned u = ((unsigned)(unsigned short)f2bf(f1) << 16) | (unsigned short)f2bf(f0);
          *(unsigned*)&A_s[wp * 32 + 2 * cp] = u;
        }
      } else {
        const short* src = (const short*)srcA + (((size_t)b * HH + hh) * WW) * CIN_A + ci0;
        for (int idx = tid; idx < 4 * 130; idx += 256) {
          int wp = idx >> 2, q = idx & 3;
          int w = wp - 1;
          short8 v = (short8)(0);
          if ((unsigned)w < (unsigned)WW)
            v = *(const short8*)(src + (size_t)w * CIN_A + q * 8);
          *(short8*)&A_s[wp * 32 + q * 8] = v;
        }
      }
      // ---- stage B: [3][128][32]
      for (int idx = tid; idx < 3 * 128 * 4; idx += 256) {
        int dx = idx / 512;
        int rem = idx - dx * 512;
        int co = rem >> 2, q = rem & 3;
        *(short8*)&B_s[(dx * 128 + co) * 32 + q * 8] =
          *(const short8*)(wbA + ((size_t)(dy * 3 + dx) * 256 + co0 + co) * CIN_A + ci0 + q * 8);
      }
      __syncthreads();
      // ---- MFMA
      #pragma unroll
      for (int dx = 0; dx < 3; dx++) {
        short8 bf[4];
        #pragma unroll
        for (int ni = 0; ni < 4; ni++)
          bf[ni] = *(const short8*)&B_s[(dx * 128 + wn * 64 + ni * 16 + lr) * 32 + lk * 8];
        #pragma unroll
        for (int mi = 0; mi < 4; mi++) {
          short8 af = *(const short8*)&A_s[(wm * 64 + mi * 16 + lr + dx) * 32 + lk * 8];
          #pragma unroll
          for (int ni = 0; ni < 4; ni++)
            acc[mi][ni] = __builtin_amdgcn_mfma_f32_16x16x32_bf16(af, bf[ni], acc[mi][ni], 0, 0, 0);
        }
      }
    }
  }

  // ---------- phase B: fused 1x1 over xB (fp32 NCHW) ----------
  if (CIN_B > 0) {
    for (int ci0 = 0; ci0 < CIN_B; ci0 += 32) {
      __syncthreads();
      const float* src = xB + ((size_t)b * CIN_B + ci0) * HWSZ + (size_t)h * WW;
      for (int idx = tid; idx < 16 * 128; idx += 256) {
        int cp = idx >> 7, w = idx & 127;
        float f0 = src[(size_t)(2 * cp) * HWSZ + w];
        float f1 = src[(size_t)(2 * cp + 1) * HWSZ + w];
        unsigned u = ((unsigned)(unsigned short)f2bf(f1) << 16) | (unsigned short)f2bf(f0);
        *(unsigned*)&A_s[w * 32 + 2 * cp] = u;
      }
      for (int idx = tid; idx < 128 * 4; idx += 256) {
        int co = idx >> 2, q = idx & 3;
        *(short8*)&B_s[co * 32 + q * 8] =
          *(const short8*)(wbB + (size_t)(co0 + co) * CIN_B + ci0 + q * 8);
      }
      __syncthreads();
      short8 bf[4];
      #pragma unroll
      for (int ni = 0; ni < 4; ni++)
        bf[ni] = *(const short8*)&B_s[(wn * 64 + ni * 16 + lr) * 32 + lk * 8];
      #pragma unroll
      for (int mi = 0; mi < 4; mi++) {
        short8 af = *(const short8*)&A_s[(wm * 64 + mi * 16 + lr) * 32 + lk * 8];
        #pragma unroll
        for (int ni = 0; ni < 4; ni++)
          acc[mi][ni] = __builtin_amdgcn_mfma_f32_16x16x32_bf16(af, bf[ni], acc[mi][ni], 0, 0, 0);
      }
    }
  }

  // ---------- epilogue: +shift, relu, store ----------
  #pragma unroll
  for (int ni = 0; ni < 4; ni++) {
    int col = wn * 64 + ni * 16 + lr;          // co within 128-tile
    float sh = shift[co0 + col];
    #pragma unroll
    for (int mi = 0; mi < 4; mi++) {
      int px = wm * 64 + mi * 16 + lk * 4;
      float4v v = acc[mi][ni];
      v.x = fmaxf(v.x + sh, 0.0f);
      v.y = fmaxf(v.y + sh, 0.0f);
      v.z = fmaxf(v.z + sh, 0.0f);
      v.w = fmaxf(v.w + sh, 0.0f);
      if (OUT_F32) {
        float* ob = (float*)out0;
        int co = co0 + col;
        *(float4v*)(ob + ((size_t)b * 256 + co) * HWSZ + (size_t)h * WW + px) = v;
      } else if (SPLIT_OUT) {
        short* ob = (short*)(nt ? out1 : out0);
        size_t base = (((size_t)b * HH + h) * WW + px) * 128 + col;
        ob[base          ] = f2bf(v.x);
        ob[base + 128    ] = f2bf(v.y);
        ob[base + 256    ] = f2bf(v.z);
        ob[base + 384    ] = f2bf(v.w);
      } else {
        short* ob = (short*)out0;
        size_t base = (((size_t)b * HH + h) * WW + px) * 256 + co0 + col;
        ob[base          ] = f2bf(v.x);
        ob[base + 256    ] = f2bf(v.y);
        ob[base + 512    ] = f2bf(v.z);
        ob[base + 768    ] = f2bf(v.w);
      }
    }
  }
}

// ---------------- reverse cummax over H on bf16 NHWC [b][h][w][128], in place
// block: 256 thr = 4 w x 64 ci-pairs; grid: (32 wchunk, 4 b)
__global__ void colscan_kernel(unsigned* __restrict__ p) {  // uint = 2 bf16
  const int t = threadIdx.x;
  const int wl = t >> 6, cp = t & 63;
  const int w = blockIdx.x * 4 + wl;
  const int b = blockIdx.y;
  float m0 = -INFINITY, m1 = -INFINITY;
  for (int h = HH - 1; h >= 0; h--) {
    size_t idx = (((size_t)b * HH + h) * WW + w) * 64 + cp;
    unsigned u = p[idx];
    float f0 = bf2f((unsigned short)(u & 0xffff));
    float f1 = bf2f((unsigned short)(u >> 16));
    m0 = fmaxf(m0, f0);
    m1 = fmaxf(m1, f1);
    p[idx] = ((unsigned)(unsigned short)f2bf(m1) << 16) | (unsigned short)f2bf(m0);
  }
}

// ---------------- reverse cummax over W on p2 + add p1 -> p1   (bf16 NHWC C=128)
// block per (b,h): 128 thr = ci; grid (128 h, 4 b)
__global__ void rowscan_add_kernel(const unsigned short* __restrict__ p2,
                                   unsigned short* __restrict__ p1) {
  const int ci = threadIdx.x;
  const int hb = blockIdx.x;
  const int b  = blockIdx.y;
  float m = -INFINITY;
  for (int w = WW - 1; w >= 0; w--) {
    size_t idx = (((size_t)b * HH + hb) * WW + w) * 128 + ci;
    m = fmaxf(m, bf2f(p2[idx]));
    float s = m + bf2f(p1[idx]);
    p1[idx] = (unsigned short)f2bf(s);
  }
}

extern "C" void kernel_launch(void* const* d_in, const int* in_sizes, int n_in,
                              void* d_out, int out_size, void* d_ws, size_t ws_size,
                              hipStream_t stream) {
  const float* x    = (const float*)d_in[0];
  const float* w_p1 = (const float*)d_in[1];
  const float* g_p1 = (const float*)d_in[2];
  const float* b_p1 = (const float*)d_in[3];
  const float* m_p1 = (const float*)d_in[4];
  const float* v_p1 = (const float*)d_in[5];
  const float* w_p2 = (const float*)d_in[6];
  const float* g_p2 = (const float*)d_in[7];
  const float* b_p2 = (const float*)d_in[8];
  const float* m_p2 = (const float*)d_in[9];
  const float* v_p2 = (const float*)d_in[10];
  const float* w_c1 = (const float*)d_in[11];
  const float* g_c1 = (const float*)d_in[12];
  const float* b_c1 = (const float*)d_in[13];
  const float* m_c1 = (const float*)d_in[14];
  const float* v_c1 = (const float*)d_in[15];
  const float* w_c2 = (const float*)d_in[16];
  const float* g_c2 = (const float*)d_in[17];
  const float* b_c2 = (const float*)d_in[18];
  const float* m_c2 = (const float*)d_in[19];
  const float* v_c2 = (const float*)d_in[20];
  const float* w_p3 = (const float*)d_in[21];
  const float* g_p3 = (const float*)d_in[22];
  const float* b_p3 = (const float*)d_in[23];
  const float* m_p3 = (const float*)d_in[24];
  const float* v_p3 = (const float*)d_in[25];

  char* ws = (char*)d_ws;
  // byte offsets
  short* p1   = (short*)(ws + 0);                    // bf16 NHWC [4][128][128][128]  16 MB
  short* p2   = (short*)(ws + 16777216);             // same                           16 MB
  short* r    = (short*)(ws + 33554432);             // bf16 NHWC [4][128][128][256]  32 MB
  short* wb12 = (short*)(ws + 67108864);             // [9][256][256]                1.18 MB
  short* wbc1 = (short*)(ws + 68288512);             // [9][256][128]                0.59 MB
  short* wbc2 = (short*)(ws + 68878336);             // [256][256]                   0.13 MB
  short* wbp3 = (short*)(ws + 69009408);             // [9][256][256]                1.18 MB
  float* prm  = (float*)(ws + 70189056);
  float* shv12 = prm + 0;     // [256] = concat(sh_p1, sh_p2)
  float* shc   = prm + 256;   // [256] = sh_c1 + sh_c2
  float* shp3  = prm + 512;
  float* sc_p1 = prm + 768;
  float* sc_p2 = prm + 896;
  float* sc_c1 = prm + 1024;
  float* sc_c2 = prm + 1280;
  float* sc_p3 = prm + 1536;
  float* shtc1 = prm + 1792;
  float* shtc2 = prm + 2048;

  fold_bn_kernel<<<1, 128, 0, stream>>>(g_p1, b_p1, m_p1, v_p1, sc_p1, shv12, 128);
  fold_bn_kernel<<<1, 128, 0, stream>>>(g_p2, b_p2, m_p2, v_p2, sc_p2, shv12 + 128, 128);
  fold_bn_kernel<<<1, 256, 0, stream>>>(g_c1, b_c1, m_c1, v_c1, sc_c1, shtc1, 256);
  fold_bn_kernel<<<1, 256, 0, stream>>>(g_c2, b_c2, m_c2, v_c2, sc_c2, shtc2, 256);
  fold_bn_kernel<<<1, 256, 0, stream>>>(g_p3, b_p3, m_p3, v_p3, sc_p3, shp3, 256);
  add_shift_kernel<<<1, 256, 0, stream>>>(shtc1, shtc2, shc);

  // weight converts (scale folded)
  wcvt3_kernel<<<(128 * 256 * 9 + 255) / 256, 256, 0, stream>>>(w_p1, sc_p1, wb12, 256, 128, 0);
  wcvt3_kernel<<<(128 * 256 * 9 + 255) / 256, 256, 0, stream>>>(w_p2, sc_p2, wb12, 256, 128, 128);
  wcvt3_kernel<<<(256 * 128 * 9 + 255) / 256, 256, 0, stream>>>(w_c1, sc_c1, wbc1, 128, 256, 0);
  wcvt1_kernel<<<(256 * 256 + 255) / 256, 256, 0, stream>>>(w_c2, sc_c2, wbc2, 256, 256);
  wcvt3_kernel<<<(256 * 256 * 9 + 255) / 256, 256, 0, stream>>>(w_p3, sc_p3, wbp3, 256, 256, 0);

  // p1|p2 = relu(bn(conv3x3(x, w_p1|w_p2)))  — fused, x read fp32-NCHW with inline cvt
  conv_mfma<true, 256, 0, true, false><<<dim3(512, 2), 256, 0, stream>>>(
      (const void*)x, nullptr, wb12, nullptr, shv12, (void*)p1, (void*)p2);

  // corner pooling
  colscan_kernel<<<dim3(32, 4), 256, 0, stream>>>((unsigned*)p1);
  rowscan_add_kernel<<<dim3(128, 4), 128, 0, stream>>>((const unsigned short*)p2,
                                                       (unsigned short*)p1);

  // r = relu(bn1(conv3x3(s,w_c1)) + bn2(conv1x1(x,w_c2)))  — 1x1 fused as phase B
  conv_mfma<false, 128, 256, false, false><<<dim3(512, 2), 256, 0, stream>>>(
      (const void*)p1, x, wbc1, wbc2, shc, (void*)r, nullptr);

  // out = relu(bn(conv3x3(r, w_p3)))  — fp32 NCHW float4 stores
  conv_mfma<false, 256, 0, false, true><<<dim3(512, 2), 256, 0, stream>>>(
      (const void*)r, nullptr, wbp3, nullptr, shp3, d_out, nullptr);
}

// Round 4
// 585.295 us; speedup vs baseline: 6.4950x; 1.2055x over previous
//
#include <hip/hip_runtime.h>
#include <math.h>

#define HH 128
#define WW 128
#define HWSZ (128*128)

typedef __attribute__((ext_vector_type(8))) short short8;
typedef __attribute__((ext_vector_type(4))) float float4v;

__device__ inline short f2bf(float f) {
  unsigned x = __float_as_uint(f);
  unsigned r = (x + 0x7fffu + ((x >> 16) & 1u)) >> 16;
  return (short)r;
}
__device__ inline float bf2f(unsigned short u) {
  return __uint_as_float(((unsigned)u) << 16);
}
// XOR-swizzled short-index of 8-short granule g in LDS row `row` (row stride 32 shorts).
// Spreads quarter-wave b128 accesses across all 32 banks (<=2-way).
__device__ inline int swz(int row, int g) {
  return row * 32 + ((g ^ ((row >> 1) & 3)) << 3);
}

// ---------------- x: NCHW fp32 -> NHWC bf16 (one-shot transpose+convert) ----
__global__ __launch_bounds__(256) void xcvt_kernel(const float* __restrict__ x,
                                                   short* __restrict__ xbf) {
  __shared__ short tile[32 * 264];
  const int t = threadIdx.x;
  const int h = blockIdx.x, b = blockIdx.y;
  for (int wc = 0; wc < 4; wc++) {
    const int w0 = wc * 32;
    __syncthreads();
    #pragma unroll
    for (int coi = 0; coi < 8; coi++) {
      int ci = coi * 32 + (t >> 3);
      int wq = t & 7;
      float4v f = *(const float4v*)&x[((size_t)b * 256 + ci) * HWSZ + h * WW + w0 + wq * 4];
      tile[(wq * 4 + 0) * 264 + ci] = f2bf(f.x);
      tile[(wq * 4 + 1) * 264 + ci] = f2bf(f.y);
      tile[(wq * 4 + 2) * 264 + ci] = f2bf(f.z);
      tile[(wq * 4 + 3) * 264 + ci] = f2bf(f.w);
    }
    __syncthreads();
    #pragma unroll
    for (int pass = 0; pass < 4; pass++) {
      int wl = pass * 8 + (t >> 5);
      int ci8 = (t & 31) * 8;
      short8 v = *(const short8*)&tile[wl * 264 + ci8];
      *(short8*)&xbf[(((size_t)b * HH + h) * WW + w0 + wl) * 256 + ci8] = v;
    }
  }
}

// ---------------- weight converts (BN scale computed inline, folded into bf16 weights)
__global__ void wcvt3_kernel(const float* __restrict__ w, const float* __restrict__ g,
                             const float* __restrict__ v, short* __restrict__ out,
                             int Cin, int CoutW, int co_off) {
  int idx = blockIdx.x * blockDim.x + threadIdx.x;
  int total = CoutW * Cin * 9;
  if (idx >= total) return;
  int t  = idx % 9;
  int ci = (idx / 9) % Cin;
  int co = idx / (9 * Cin);
  float s = g[co] * rsqrtf(v[co] + 1e-5f);
  out[((size_t)t * 256 + co_off + co) * Cin + ci] = f2bf(w[idx] * s);
}

__global__ void wcvt1_kernel(const float* __restrict__ w, const float* __restrict__ g,
                             const float* __restrict__ v, short* __restrict__ out,
                             int Cin, int CoutW) {
  int idx = blockIdx.x * blockDim.x + threadIdx.x;
  if (idx >= CoutW * Cin) return;
  int co = idx / Cin;
  float s = g[co] * rsqrtf(v[co] + 1e-5f);
  out[idx] = f2bf(w[idx] * s);
}

// ---------------- MFMA implicit-GEMM conv3x3 (+optional fused 1x1 phase) ----------------
// Block: 256 thr = 4 waves (2x2). Tile: M=128 px (one image row) x N=128 co.
// grid.x = b*128 + h, grid.y = n-tile. A LDS [130 wpad][32 ci], B LDS [3 dx][128 co][32 ci],
// both XOR-granule-swizzled. Weights carry BN scale; epilogue adds shift (from raw BN params).
// SHIFT_MODE: 0 single(set0[c]), 1 split(c<128 ? set0[c] : set1[c-128]), 2 sum(set0[c]+set1[c]).
template<int CIN_A, bool PHASE_B, int SHIFT_MODE, bool SPLIT_OUT, bool OUT_F32>
__global__ __launch_bounds__(256) void conv_mfma(
    const short* __restrict__ srcA, const short* __restrict__ xB,
    const short* __restrict__ wbA, const short* __restrict__ wbB,
    const float* __restrict__ g0, const float* __restrict__ b0,
    const float* __restrict__ m0, const float* __restrict__ v0,
    const float* __restrict__ g1, const float* __restrict__ b1,
    const float* __restrict__ m1, const float* __restrict__ v1,
    void* __restrict__ out0, void* __restrict__ out1)
{
  __shared__ short A_s[130 * 32];
  __shared__ short B_s[3 * 128 * 32];

  const int tid  = threadIdx.x;
  const int wave = tid >> 6;
  const int lane = tid & 63;
  const int wm = wave & 1;
  const int wn = wave >> 1;
  const int lr = lane & 15;
  const int lk = lane >> 4;

  const int h  = blockIdx.x & 127;
  const int b  = blockIdx.x >> 7;
  const int nt = blockIdx.y;
  const int co0 = nt * 128;

  float4v acc[4][4];
  #pragma unroll
  for (int i = 0; i < 4; i++)
    #pragma unroll
    for (int j = 0; j < 4; j++) acc[i][j] = (float4v)(0.0f);

  // ---------- phase A: 3x3 over srcA (bf16 NHWC, C=CIN_A) ----------
  for (int dy = 0; dy < 3; dy++) {
    int hh = h + dy - 1;
    if (hh < 0 || hh >= HH) continue;          // block-uniform
    const short* srcRow = srcA + (((size_t)b * HH + hh) * WW) * CIN_A;
    for (int ci0 = 0; ci0 < CIN_A; ci0 += 32) {
      __syncthreads();
      for (int idx = tid; idx < 4 * 130; idx += 256) {
        int wp = idx >> 2, q = idx & 3;
        int w = wp - 1;
        short8 val = (short8)(0);
        if ((unsigned)w < (unsigned)WW)
          val = *(const short8*)(srcRow + (size_t)w * CIN_A + ci0 + q * 8);
        *(short8*)&A_s[swz(wp, q)] = val;
      }
      for (int idx = tid; idx < 3 * 128 * 4; idx += 256) {
        int dx = idx / 512;
        int rem = idx - dx * 512;
        int co = rem >> 2, q = rem & 3;
        *(short8*)&B_s[swz(dx * 128 + co, q)] =
          *(const short8*)(wbA + ((size_t)(dy * 3 + dx) * 256 + co0 + co) * CIN_A + ci0 + q * 8);
      }
      __syncthreads();
      #pragma unroll
      for (int dx = 0; dx < 3; dx++) {
        short8 bfr[4];
        #pragma unroll
        for (int ni = 0; ni < 4; ni++)
          bfr[ni] = *(const short8*)&B_s[swz(dx * 128 + wn * 64 + ni * 16 + lr, lk)];
        #pragma unroll
        for (int mi = 0; mi < 4; mi++) {
          short8 af = *(const short8*)&A_s[swz(wm * 64 + mi * 16 + lr + dx, lk)];
          #pragma unroll
          for (int ni = 0; ni < 4; ni++)
            acc[mi][ni] = __builtin_amdgcn_mfma_f32_16x16x32_bf16(af, bfr[ni], acc[mi][ni], 0, 0, 0);
        }
      }
    }
  }

  // ---------- phase B: fused 1x1 over xB (bf16 NHWC, C=256) ----------
  if (PHASE_B) {
    const short* srcRow = xB + (((size_t)b * HH + h) * WW) * 256;
    for (int ci0 = 0; ci0 < 256; ci0 += 32) {
      __syncthreads();
      for (int idx = tid; idx < 4 * 128; idx += 256) {
        int wp = idx >> 2, q = idx & 3;
        *(short8*)&A_s[swz(wp, q)] =
          *(const short8*)(srcRow + (size_t)wp * 256 + ci0 + q * 8);
      }
      for (int idx = tid; idx < 128 * 4; idx += 256) {
        int co = idx >> 2, q = idx & 3;
        *(short8*)&B_s[swz(co, q)] =
          *(const short8*)(wbB + (size_t)(co0 + co) * 256 + ci0 + q * 8);
      }
      __syncthreads();
      short8 bfr[4];
      #pragma unroll
      for (int ni = 0; ni < 4; ni++)
        bfr[ni] = *(const short8*)&B_s[swz(wn * 64 + ni * 16 + lr, lk)];
      #pragma unroll
      for (int mi = 0; mi < 4; mi++) {
        short8 af = *(const short8*)&A_s[swz(wm * 64 + mi * 16 + lr, lk)];
        #pragma unroll
        for (int ni = 0; ni < 4; ni++)
          acc[mi][ni] = __builtin_amdgcn_mfma_f32_16x16x32_bf16(af, bfr[ni], acc[mi][ni], 0, 0, 0);
      }
    }
  }

  // ---------- epilogue: +shift (from raw BN params), relu, store ----------
  #pragma unroll
  for (int ni = 0; ni < 4; ni++) {
    int col = wn * 64 + ni * 16 + lr;
    int c = co0 + col;
    float sh;
    if (SHIFT_MODE == 0) {
      float s = g0[c] * rsqrtf(v0[c] + 1e-5f);
      sh = b0[c] - m0[c] * s;
    } else if (SHIFT_MODE == 1) {
      int cc = c & 127;
      const float* gg = (c < 128) ? g0 : g1;
      const float* bb = (c < 128) ? b0 : b1;
      const float* mm = (c < 128) ? m0 : m1;
      const float* vv = (c < 128) ? v0 : v1;
      float s = gg[cc] * rsqrtf(vv[cc] + 1e-5f);
      sh = bb[cc] - mm[cc] * s;
    } else {
      float s0 = g0[c] * rsqrtf(v0[c] + 1e-5f);
      float s1 = g1[c] * rsqrtf(v1[c] + 1e-5f);
      sh = (b0[c] - m0[c] * s0) + (b1[c] - m1[c] * s1);
    }
    #pragma unroll
    for (int mi = 0; mi < 4; mi++) {
      int px = wm * 64 + mi * 16 + lk * 4;
      float4v v = acc[mi][ni];
      v.x = fmaxf(v.x + sh, 0.0f);
      v.y = fmaxf(v.y + sh, 0.0f);
      v.z = fmaxf(v.z + sh, 0.0f);
      v.w = fmaxf(v.w + sh, 0.0f);
      if (OUT_F32) {
        float* ob = (float*)out0;
        *(float4v*)(ob + ((size_t)b * 256 + c) * HWSZ + (size_t)h * WW + px) = v;
      } else if (SPLIT_OUT) {
        short* ob = (short*)(nt ? out1 : out0);
        size_t base = (((size_t)b * HH + h) * WW + px) * 128 + col;
        ob[base      ] = f2bf(v.x);
        ob[base + 128 ] = f2bf(v.y);
        ob[base + 256 ] = f2bf(v.z);
        ob[base + 384 ] = f2bf(v.w);
      } else {
        short* ob = (short*)out0;
        size_t base = (((size_t)b * HH + h) * WW + px) * 256 + c;
        ob[base      ] = f2bf(v.x);
        ob[base + 256 ] = f2bf(v.y);
        ob[base + 512 ] = f2bf(v.z);
        ob[base + 768 ] = f2bf(v.w);
      }
    }
  }
}

// ---------------- reverse cummax over H on bf16 NHWC [b][h][w][128], in place
__global__ void colscan_kernel(unsigned* __restrict__ p) {  // uint = 2 bf16
  const int t = threadIdx.x;
  const int wl = t >> 6, cp = t & 63;
  const int w = blockIdx.x * 4 + wl;
  const int b = blockIdx.y;
  float m0 = -INFINITY, m1 = -INFINITY;
  for (int h = HH - 1; h >= 0; h--) {
    size_t idx = (((size_t)b * HH + h) * WW + w) * 64 + cp;
    unsigned u = p[idx];
    float f0 = bf2f((unsigned short)(u & 0xffff));
    float f1 = bf2f((unsigned short)(u >> 16));
    m0 = fmaxf(m0, f0);
    m1 = fmaxf(m1, f1);
    p[idx] = ((unsigned)(unsigned short)f2bf(m1) << 16) | (unsigned short)f2bf(m0);
  }
}

// ---------------- reverse cummax over W on p2 + add p1 -> p1   (bf16 NHWC C=128)
__global__ void rowscan_add_kernel(const unsigned short* __restrict__ p2,
                                   unsigned short* __restrict__ p1) {
  const int ci = threadIdx.x;
  const int hb = blockIdx.x;
  const int b  = blockIdx.y;
  float m = -INFINITY;
  for (int w = WW - 1; w >= 0; w--) {
    size_t idx = (((size_t)b * HH + hb) * WW + w) * 128 + ci;
    m = fmaxf(m, bf2f(p2[idx]));
    float s = m + bf2f(p1[idx]);
    p1[idx] = (unsigned short)f2bf(s);
  }
}

extern "C" void kernel_launch(void* const* d_in, const int* in_sizes, int n_in,
                              void* d_out, int out_size, void* d_ws, size_t ws_size,
                              hipStream_t stream) {
  const float* x    = (const float*)d_in[0];
  const float* w_p1 = (const float*)d_in[1];
  const float* g_p1 = (const float*)d_in[2];
  const float* b_p1 = (const float*)d_in[3];
  const float* m_p1 = (const float*)d_in[4];
  const float* v_p1 = (const float*)d_in[5];
  const float* w_p2 = (const float*)d_in[6];
  const float* g_p2 = (const float*)d_in[7];
  const float* b_p2 = (const float*)d_in[8];
  const float* m_p2 = (const float*)d_in[9];
  const float* v_p2 = (const float*)d_in[10];
  const float* w_c1 = (const float*)d_in[11];
  const float* g_c1 = (const float*)d_in[12];
  const float* b_c1 = (const float*)d_in[13];
  const float* m_c1 = (const float*)d_in[14];
  const float* v_c1 = (const float*)d_in[15];
  const float* w_c2 = (const float*)d_in[16];
  const float* g_c2 = (const float*)d_in[17];
  const float* b_c2 = (const float*)d_in[18];
  const float* m_c2 = (const float*)d_in[19];
  const float* v_c2 = (const float*)d_in[20];
  const float* w_p3 = (const float*)d_in[21];
  const float* g_p3 = (const float*)d_in[22];
  const float* b_p3 = (const float*)d_in[23];
  const float* m_p3 = (const float*)d_in[24];
  const float* v_p3 = (const float*)d_in[25];

  char* ws = (char*)d_ws;
  // Persistent tensors — total exactly 100,663,296 B (== R2-proven footprint).
  short* p1  = (short*)(ws + 0);          // bf16 NHWC [4][128][128][128]  16 MB
  short* p2  = (short*)(ws + 16777216);   // bf16 NHWC [4][128][128][128]  16 MB
  short* r   = (short*)(ws + 33554432);   // bf16 NHWC [4][128][128][256]  32 MB
  short* xbf = (short*)(ws + 67108864);   // bf16 NHWC [4][128][128][256]  32 MB
  // Weight buffers overlay dead regions (stream-ordered):
  short* wb12 = r;                        // [9][256][256] 1.18 MB; dead before c1 writes r
  short* wbc1 = p2;                       // [9][256][128] 0.59 MB; written after rowscan_add
  short* wbc2 = (short*)(ws + 16777216 + 589824);  // [256][256] 0.13 MB, in p2 region
  short* wbp3 = p1;                       // [9][256][256] 1.18 MB; written after c1

  // x -> NHWC bf16
  xcvt_kernel<<<dim3(128, 4), 256, 0, stream>>>(x, xbf);

  // weights for p1|p2 (into r region)
  wcvt3_kernel<<<(128 * 256 * 9 + 255) / 256, 256, 0, stream>>>(w_p1, g_p1, v_p1, wb12, 256, 128, 0);
  wcvt3_kernel<<<(128 * 256 * 9 + 255) / 256, 256, 0, stream>>>(w_p2, g_p2, v_p2, wb12, 256, 128, 128);

  // p1|p2 = relu(bn(conv3x3(x)))
  conv_mfma<256, false, 1, true, false><<<dim3(512, 2), 256, 0, stream>>>(
      xbf, nullptr, wb12, nullptr,
      g_p1, b_p1, m_p1, v_p1, g_p2, b_p2, m_p2, v_p2, (void*)p1, (void*)p2);

  // corner pooling: cp1 in-place on p1, then s = rowscan(p2) + cp1 -> p1
  colscan_kernel<<<dim3(32, 4), 256, 0, stream>>>((unsigned*)p1);
  rowscan_add_kernel<<<dim3(128, 4), 128, 0, stream>>>((const unsigned short*)p2,
                                                       (unsigned short*)p1);

  // weights for c1 (3x3) and c2 (1x1) into p2 region (p2 dead now)
  wcvt3_kernel<<<(256 * 128 * 9 + 255) / 256, 256, 0, stream>>>(w_c1, g_c1, v_c1, wbc1, 128, 256, 0);
  wcvt1_kernel<<<(256 * 256 + 255) / 256, 256, 0, stream>>>(w_c2, g_c2, v_c2, wbc2, 256, 256);

  // r = relu(bn1(conv3x3(s)) + bn2(conv1x1(x)))
  conv_mfma<128, true, 2, false, false><<<dim3(512, 2), 256, 0, stream>>>(
      p1, xbf, wbc1, wbc2,
      g_c1, b_c1, m_c1, v_c1, g_c2, b_c2, m_c2, v_c2, (void*)r, nullptr);

  // weights for p3 into p1 region (p1 dead now)
  wcvt3_kernel<<<(256 * 256 * 9 + 255) / 256, 256, 0, stream>>>(w_p3, g_p3, v_p3, wbp3, 256, 256, 0);

  // out = relu(bn(conv3x3(r)))  — fp32 NCHW float4 stores
  conv_mfma<256, false, 0, false, true><<<dim3(512, 2), 256, 0, stream>>>(
      r, nullptr, wbp3, nullptr,
      g_p3, b_p3, m_p3, v_p3, nullptr, nullptr, nullptr, nullptr, d_out, nullptr);
}

// Round 5
// 436.890 us; speedup vs baseline: 8.7013x; 1.3397x over previous
//
#include <hip/hip_runtime.h>
#include <math.h>

#define HH 128
#define WW 128
#define HWSZ (128*128)

typedef __attribute__((ext_vector_type(8))) short short8;
typedef __attribute__((ext_vector_type(4))) float float4v;

__device__ inline short f2bf(float f) {
  unsigned x = __float_as_uint(f);
  unsigned r = (x + 0x7fffu + ((x >> 16) & 1u)) >> 16;
  return (short)r;
}
__device__ inline float bf2f(unsigned short u) {
  return __uint_as_float(((unsigned)u) << 16);
}
// XOR-swizzled short-index of 8-short granule g in LDS row `row` (row stride 32 shorts).
__device__ inline int swz(int row, int g) {
  return row * 32 + ((g ^ ((row >> 1) & 3)) << 3);
}

// ---------------- x: NCHW fp32 -> NHWC bf16 ----
__global__ __launch_bounds__(256) void xcvt_kernel(const float* __restrict__ x,
                                                   short* __restrict__ xbf) {
  __shared__ short tile[32 * 264];
  const int t = threadIdx.x;
  const int h = blockIdx.x, b = blockIdx.y;
  for (int wc = 0; wc < 4; wc++) {
    const int w0 = wc * 32;
    __syncthreads();
    #pragma unroll
    for (int coi = 0; coi < 8; coi++) {
      int ci = coi * 32 + (t >> 3);
      int wq = t & 7;
      float4v f = *(const float4v*)&x[((size_t)b * 256 + ci) * HWSZ + h * WW + w0 + wq * 4];
      tile[(wq * 4 + 0) * 264 + ci] = f2bf(f.x);
      tile[(wq * 4 + 1) * 264 + ci] = f2bf(f.y);
      tile[(wq * 4 + 2) * 264 + ci] = f2bf(f.z);
      tile[(wq * 4 + 3) * 264 + ci] = f2bf(f.w);
    }
    __syncthreads();
    #pragma unroll
    for (int pass = 0; pass < 4; pass++) {
      int wl = pass * 8 + (t >> 5);
      int ci8 = (t & 31) * 8;
      short8 v = *(const short8*)&tile[wl * 264 + ci8];
      *(short8*)&xbf[(((size_t)b * HH + h) * WW + w0 + wl) * 256 + ci8] = v;
    }
  }
}

// ---------------- weight converts (BN scale folded) ----
__global__ void wcvt3_kernel(const float* __restrict__ w, const float* __restrict__ g,
                             const float* __restrict__ v, short* __restrict__ out,
                             int Cin, int CoutW, int co_off) {
  int idx = blockIdx.x * blockDim.x + threadIdx.x;
  int total = CoutW * Cin * 9;
  if (idx >= total) return;
  int t  = idx % 9;
  int ci = (idx / 9) % Cin;
  int co = idx / (9 * Cin);
  float s = g[co] * rsqrtf(v[co] + 1e-5f);
  out[((size_t)t * 256 + co_off + co) * Cin + ci] = f2bf(w[idx] * s);
}

__global__ void wcvt1_kernel(const float* __restrict__ w, const float* __restrict__ g,
                             const float* __restrict__ v, short* __restrict__ out,
                             int Cin, int CoutW) {
  int idx = blockIdx.x * blockDim.x + threadIdx.x;
  if (idx >= CoutW * Cin) return;
  int co = idx / Cin;
  float s = g[co] * rsqrtf(v[co] + 1e-5f);
  out[idx] = f2bf(w[idx] * s);
}

// ---------------- MFMA implicit-GEMM conv3x3 (+optional fused 1x1), SW-pipelined ----------------
// Block: 256 thr = 4 waves (2x2). Tile: M=128 px (one image row) x N=128 co.
// K-loop flattened into chunks: phase A = (dy valid) x (CIN_A/32), phase B = 8.
// Pipeline: regs hold chunk t+1's global data while MFMA consumes chunk t from LDS.
template<int CIN_A, bool PHASE_B, int SHIFT_MODE, bool SPLIT_OUT, bool OUT_F32>
__global__ __launch_bounds__(256) void conv_mfma(
    const short* __restrict__ srcA, const short* __restrict__ xB,
    const short* __restrict__ wbA, const short* __restrict__ wbB,
    const float* __restrict__ g0, const float* __restrict__ b0,
    const float* __restrict__ m0, const float* __restrict__ v0,
    const float* __restrict__ g1, const float* __restrict__ b1,
    const float* __restrict__ m1, const float* __restrict__ v1,
    void* __restrict__ out0, void* __restrict__ out1)
{
  __shared__ short A_s[130 * 32];
  __shared__ short B_s[3 * 128 * 32];

  const int tid  = threadIdx.x;
  const int wave = tid >> 6;
  const int lane = tid & 63;
  const int wm = wave & 1;
  const int wn = wave >> 1;
  const int lr = lane & 15;
  const int lk = lane >> 4;

  const int h  = blockIdx.x & 127;
  const int b  = blockIdx.x >> 7;
  const int nt = blockIdx.y;
  const int co0 = nt * 128;

  constexpr int ncA = CIN_A / 32;
  const int dystart = (h == 0) ? 1 : 0;
  const int dyend   = (h == HH - 1) ? 2 : 3;
  const int chunksA = (dyend - dystart) * ncA;
  const int total   = chunksA + (PHASE_B ? 8 : 0);

  float4v acc[4][4];
  #pragma unroll
  for (int i = 0; i < 4; i++)
    #pragma unroll
    for (int j = 0; j < 4; j++) acc[i][j] = (float4v)(0.0f);

  // pipeline registers
  short8 rA[3], rB[6];
  const short* aRow = nullptr;
  const short* bBase = nullptr;
  bool curIsA = true;

  auto decode = [&](int t, const short*& ar, const short*& bb, bool& isA) {
    isA = (t < chunksA);
    if (isA) {
      int dy  = dystart + t / ncA;
      int ci0 = (t % ncA) * 32;
      ar = srcA + (((size_t)b * HH + (h + dy - 1)) * WW) * CIN_A + ci0;
      bb = wbA + ((size_t)(dy * 3) * 256 + co0) * CIN_A + ci0;
    } else {
      int ci0 = (t - chunksA) * 32;
      ar = xB + (((size_t)b * HH + h) * WW) * 256 + ci0;
      bb = wbB + (size_t)co0 * 256 + ci0;
    }
  };

  auto loadRegs = [&](const short* ar, const short* bb, bool isA) {
    if (isA) {
      #pragma unroll
      for (int i = 0; i < 2; i++) {
        int idx = tid + i * 256;
        int w = (idx >> 2) - 1, q = idx & 3;
        rA[i] = ((unsigned)w < (unsigned)WW)
                  ? *(const short8*)(ar + (size_t)w * CIN_A + q * 8) : (short8)(0);
      }
      {
        int idx = tid + 512;
        int w = (idx >> 2) - 1, q = idx & 3;
        if (tid < 8)
          rA[2] = ((unsigned)w < (unsigned)WW)
                    ? *(const short8*)(ar + (size_t)w * CIN_A + q * 8) : (short8)(0);
      }
      #pragma unroll
      for (int i = 0; i < 6; i++) {
        int idx = tid + i * 256;
        int dx = idx >> 9, rem = idx & 511;
        int co = rem >> 2, q = rem & 3;
        rB[i] = *(const short8*)(bb + (size_t)(dx * 256 + co) * CIN_A + q * 8);
      }
    } else {
      #pragma unroll
      for (int i = 0; i < 2; i++) {
        int idx = tid + i * 256;
        int wp = idx >> 2, q = idx & 3;
        rA[i] = *(const short8*)(ar + (size_t)wp * 256 + q * 8);
      }
      #pragma unroll
      for (int i = 0; i < 2; i++) {
        int idx = tid + i * 256;
        int co = idx >> 2, q = idx & 3;
        rB[i] = *(const short8*)(bb + (size_t)co * 256 + q * 8);
      }
    }
  };

  auto storeLDS = [&](bool isA) {
    if (isA) {
      #pragma unroll
      for (int i = 0; i < 2; i++) {
        int idx = tid + i * 256;
        *(short8*)&A_s[swz(idx >> 2, idx & 3)] = rA[i];
      }
      if (tid < 8) {
        int idx = tid + 512;
        *(short8*)&A_s[swz(idx >> 2, idx & 3)] = rA[2];
      }
      #pragma unroll
      for (int i = 0; i < 6; i++) {
        int idx = tid + i * 256;
        int dx = idx >> 9, rem = idx & 511;
        *(short8*)&B_s[swz(dx * 128 + (rem >> 2), rem & 3)] = rB[i];
      }
    } else {
      #pragma unroll
      for (int i = 0; i < 2; i++) {
        int idx = tid + i * 256;
        *(short8*)&A_s[swz(idx >> 2, idx & 3)] = rA[i];
      }
      #pragma unroll
      for (int i = 0; i < 2; i++) {
        int idx = tid + i * 256;
        *(short8*)&B_s[swz(idx >> 2, idx & 3)] = rB[i];
      }
    }
  };

  // prologue: load chunk 0
  decode(0, aRow, bBase, curIsA);
  loadRegs(aRow, bBase, curIsA);

  for (int t = 0; t < total; t++) {
    bool isA = curIsA;
    __syncthreads();            // previous MFMA done reading LDS
    storeLDS(isA);              // waits on this chunk's global loads
    __syncthreads();
    if (t + 1 < total) {        // issue next chunk's loads; overlap with MFMA below
      decode(t + 1, aRow, bBase, curIsA);
      loadRegs(aRow, bBase, curIsA);
    }
    // ---- MFMA on chunk t (phase A: dx 0..2 with shifted A window & wp=w+1;
    //      phase B: dx=0 only, A rows staged at w directly)
    const int ndx = isA ? 3 : 1;
    for (int dx = 0; dx < ndx; dx++) {
      short8 bfr[4];
      #pragma unroll
      for (int ni = 0; ni < 4; ni++)
        bfr[ni] = *(const short8*)&B_s[swz(dx * 128 + wn * 64 + ni * 16 + lr, lk)];
      #pragma unroll
      for (int mi = 0; mi < 4; mi++) {
        short8 af = *(const short8*)&A_s[swz(wm * 64 + mi * 16 + lr + dx, lk)];
        #pragma unroll
        for (int ni = 0; ni < 4; ni++)
          acc[mi][ni] = __builtin_amdgcn_mfma_f32_16x16x32_bf16(af, bfr[ni], acc[mi][ni], 0, 0, 0);
      }
    }
  }

  // ---------- epilogue: +shift (from raw BN params), relu, store ----------
  #pragma unroll
  for (int ni = 0; ni < 4; ni++) {
    int col = wn * 64 + ni * 16 + lr;
    int c = co0 + col;
    float sh;
    if (SHIFT_MODE == 0) {
      float s = g0[c] * rsqrtf(v0[c] + 1e-5f);
      sh = b0[c] - m0[c] * s;
    } else if (SHIFT_MODE == 1) {
      int cc = c & 127;
      const float* gg = (c < 128) ? g0 : g1;
      const float* bb = (c < 128) ? b0 : b1;
      const float* mm = (c < 128) ? m0 : m1;
      const float* vv = (c < 128) ? v0 : v1;
      float s = gg[cc] * rsqrtf(vv[cc] + 1e-5f);
      sh = bb[cc] - mm[cc] * s;
    } else {
      float s0 = g0[c] * rsqrtf(v0[c] + 1e-5f);
      float s1 = g1[c] * rsqrtf(v1[c] + 1e-5f);
      sh = (b0[c] - m0[c] * s0) + (b1[c] - m1[c] * s1);
    }
    #pragma unroll
    for (int mi = 0; mi < 4; mi++) {
      int px = wm * 64 + mi * 16 + lk * 4;
      float4v v = acc[mi][ni];
      v.x = fmaxf(v.x + sh, 0.0f);
      v.y = fmaxf(v.y + sh, 0.0f);
      v.z = fmaxf(v.z + sh, 0.0f);
      v.w = fmaxf(v.w + sh, 0.0f);
      if (OUT_F32) {
        float* ob = (float*)out0;
        *(float4v*)(ob + ((size_t)b * 256 + c) * HWSZ + (size_t)h * WW + px) = v;
      } else if (SPLIT_OUT) {
        short* ob = (short*)(nt ? out1 : out0);
        size_t base = (((size_t)b * HH + h) * WW + px) * 128 + col;
        ob[base      ] = f2bf(v.x);
        ob[base + 128 ] = f2bf(v.y);
        ob[base + 256 ] = f2bf(v.z);
        ob[base + 384 ] = f2bf(v.w);
      } else {
        short* ob = (short*)out0;
        size_t base = (((size_t)b * HH + h) * WW + px) * 256 + c;
        ob[base      ] = f2bf(v.x);
        ob[base + 256 ] = f2bf(v.y);
        ob[base + 512 ] = f2bf(v.z);
        ob[base + 768 ] = f2bf(v.w);
      }
    }
  }
}

// ---------------- reverse cummax over H on bf16 NHWC [b][h][w][128], in place
__global__ void colscan_kernel(unsigned* __restrict__ p) {  // uint = 2 bf16
  const int t = threadIdx.x;
  const int wl = t >> 6, cp = t & 63;
  const int w = blockIdx.x * 4 + wl;
  const int b = blockIdx.y;
  float m0 = -INFINITY, m1 = -INFINITY;
  for (int h = HH - 1; h >= 0; h--) {
    size_t idx = (((size_t)b * HH + h) * WW + w) * 64 + cp;
    unsigned u = p[idx];
    float f0 = bf2f((unsigned short)(u & 0xffff));
    float f1 = bf2f((unsigned short)(u >> 16));
    m0 = fmaxf(m0, f0);
    m1 = fmaxf(m1, f1);
    p[idx] = ((unsigned)(unsigned short)f2bf(m1) << 16) | (unsigned short)f2bf(m0);
  }
}

// ---------------- reverse cummax over W on p2 + add p1 -> p1 (bf16 NHWC C=128)
// LDS-tiled: coalesced b128 load of the [128 w][128 ci] plane, serial scan in LDS
// (conflict-free: at each w, 128 lanes read 256 consecutive bytes), coalesced add+store.
__global__ __launch_bounds__(256) void rowscan_add_kernel(
    const short* __restrict__ p2, short* __restrict__ p1) {
  __shared__ short pl[128 * 128];
  const int tid = threadIdx.x;
  const int hb = blockIdx.x;
  const int b  = blockIdx.y;
  const size_t base = (((size_t)b * HH + hb) * WW) * 128;

  #pragma unroll
  for (int i = 0; i < 8; i++) {
    int idx = tid + i * 256;          // granule of 8 shorts
    *(short8*)&pl[idx * 8] = *(const short8*)(p2 + base + (size_t)idx * 8);
  }
  __syncthreads();
  if (tid < 128) {
    float m = -INFINITY;
    for (int w = WW - 1; w >= 0; w--) {
      int a = w * 128 + tid;
      m = fmaxf(m, bf2f((unsigned short)pl[a]));
      pl[a] = (short)f2bf(m);
    }
  }
  __syncthreads();
  #pragma unroll
  for (int i = 0; i < 8; i++) {
    int idx = tid + i * 256;
    short8 sv = *(const short8*)&pl[idx * 8];
    short8 ov = *(const short8*)(p1 + base + (size_t)idx * 8);
    short8 rv;
    #pragma unroll
    for (int j = 0; j < 8; j++)
      rv[j] = f2bf(bf2f((unsigned short)sv[j]) + bf2f((unsigned short)ov[j]));
    *(short8*)(p1 + base + (size_t)idx * 8) = rv;
  }
}

extern "C" void kernel_launch(void* const* d_in, const int* in_sizes, int n_in,
                              void* d_out, int out_size, void* d_ws, size_t ws_size,
                              hipStream_t stream) {
  const float* x    = (const float*)d_in[0];
  const float* w_p1 = (const float*)d_in[1];
  const float* g_p1 = (const float*)d_in[2];
  const float* b_p1 = (const float*)d_in[3];
  const float* m_p1 = (const float*)d_in[4];
  const float* v_p1 = (const float*)d_in[5];
  const float* w_p2 = (const float*)d_in[6];
  const float* g_p2 = (const float*)d_in[7];
  const float* b_p2 = (const float*)d_in[8];
  const float* m_p2 = (const float*)d_in[9];
  const float* v_p2 = (const float*)d_in[10];
  const float* w_c1 = (const float*)d_in[11];
  const float* g_c1 = (const float*)d_in[12];
  const float* b_c1 = (const float*)d_in[13];
  const float* m_c1 = (const float*)d_in[14];
  const float* v_c1 = (const float*)d_in[15];
  const float* w_c2 = (const float*)d_in[16];
  const float* g_c2 = (const float*)d_in[17];
  const float* b_c2 = (const float*)d_in[18];
  const float* m_c2 = (const float*)d_in[19];
  const float* v_c2 = (const float*)d_in[20];
  const float* w_p3 = (const float*)d_in[21];
  const float* g_p3 = (const float*)d_in[22];
  const float* b_p3 = (const float*)d_in[23];
  const float* m_p3 = (const float*)d_in[24];
  const float* v_p3 = (const float*)d_in[25];

  char* ws = (char*)d_ws;
  // Persistent tensors — total exactly 100,663,296 B.
  short* p1  = (short*)(ws + 0);          // bf16 NHWC [4][128][128][128]  16 MB
  short* p2  = (short*)(ws + 16777216);   // bf16 NHWC [4][128][128][128]  16 MB
  short* r   = (short*)(ws + 33554432);   // bf16 NHWC [4][128][128][256]  32 MB
  short* xbf = (short*)(ws + 67108864);   // bf16 NHWC [4][128][128][256]  32 MB
  // Weight buffers overlay dead regions (stream-ordered):
  short* wb12 = r;                        // [9][256][256]; dead before c1 writes r
  short* wbc1 = p2;                       // [9][256][128]; written after rowscan_add
  short* wbc2 = (short*)(ws + 16777216 + 589824);  // [256][256], in p2 region
  short* wbp3 = p1;                       // [9][256][256]; written after c1

  // x -> NHWC bf16
  xcvt_kernel<<<dim3(128, 4), 256, 0, stream>>>(x, xbf);

  // weights for p1|p2 (into r region)
  wcvt3_kernel<<<(128 * 256 * 9 + 255) / 256, 256, 0, stream>>>(w_p1, g_p1, v_p1, wb12, 256, 128, 0);
  wcvt3_kernel<<<(128 * 256 * 9 + 255) / 256, 256, 0, stream>>>(w_p2, g_p2, v_p2, wb12, 256, 128, 128);

  // p1|p2 = relu(bn(conv3x3(x)))
  conv_mfma<256, false, 1, true, false><<<dim3(512, 2), 256, 0, stream>>>(
      xbf, nullptr, wb12, nullptr,
      g_p1, b_p1, m_p1, v_p1, g_p2, b_p2, m_p2, v_p2, (void*)p1, (void*)p2);

  // corner pooling: cp1 in-place on p1, then s = rowscan(p2) + cp1 -> p1
  colscan_kernel<<<dim3(32, 4), 256, 0, stream>>>((unsigned*)p1);
  rowscan_add_kernel<<<dim3(128, 4), 256, 0, stream>>>(p2, p1);

  // weights for c1 (3x3) and c2 (1x1) into p2 region (p2 dead now)
  wcvt3_kernel<<<(256 * 128 * 9 + 255) / 256, 256, 0, stream>>>(w_c1, g_c1, v_c1, wbc1, 128, 256, 0);
  wcvt1_kernel<<<(256 * 256 + 255) / 256, 256, 0, stream>>>(w_c2, g_c2, v_c2, wbc2, 256, 256);

  // r = relu(bn1(conv3x3(s)) + bn2(conv1x1(x)))
  conv_mfma<128, true, 2, false, false><<<dim3(512, 2), 256, 0, stream>>>(
      p1, xbf, wbc1, wbc2,
      g_c1, b_c1, m_c1, v_c1, g_c2, b_c2, m_c2, v_c2, (void*)r, nullptr);

  // weights for p3 into p1 region (p1 dead now)
  wcvt3_kernel<<<(256 * 256 * 9 + 255) / 256, 256, 0, stream>>>(w_p3, g_p3, v_p3, wbp3, 256, 256, 0);

  // out = relu(bn(conv3x3(r)))  — fp32 NCHW float4 stores
  conv_mfma<256, false, 0, false, true><<<dim3(512, 2), 256, 0, stream>>>(
      r, nullptr, wbp3, nullptr,
      g_p3, b_p3, m_p3, v_p3, nullptr, nullptr, nullptr, nullptr, d_out, nullptr);
}

// Round 6
// 427.662 us; speedup vs baseline: 8.8890x; 1.0216x over previous
//
#include <hip/hip_runtime.h>
#include <math.h>

#define HH 128
#define WW 128
#define HWSZ (128*128)

typedef __attribute__((ext_vector_type(8))) short short8;
typedef __attribute__((ext_vector_type(4))) float float4v;

__device__ inline short f2bf(float f) {
  unsigned x = __float_as_uint(f);
  unsigned r = (x + 0x7fffu + ((x >> 16) & 1u)) >> 16;
  return (short)r;
}
__device__ inline float bf2f(unsigned short u) {
  return __uint_as_float(((unsigned)u) << 16);
}
// XOR-swizzled short-index of 8-short granule g in LDS row `row` (row stride 32 shorts).
__device__ inline int swz(int row, int g) {
  return row * 32 + ((g ^ ((row >> 1) & 3)) << 3);
}

// ---------------- x: NCHW fp32 -> NHWC bf16 ----
__global__ __launch_bounds__(256) void xcvt_kernel(const float* __restrict__ x,
                                                   short* __restrict__ xbf) {
  __shared__ short tile[32 * 264];
  const int t = threadIdx.x;
  const int h = blockIdx.x, b = blockIdx.y;
  for (int wc = 0; wc < 4; wc++) {
    const int w0 = wc * 32;
    __syncthreads();
    #pragma unroll
    for (int coi = 0; coi < 8; coi++) {
      int ci = coi * 32 + (t >> 3);
      int wq = t & 7;
      float4v f = *(const float4v*)&x[((size_t)b * 256 + ci) * HWSZ + h * WW + w0 + wq * 4];
      tile[(wq * 4 + 0) * 264 + ci] = f2bf(f.x);
      tile[(wq * 4 + 1) * 264 + ci] = f2bf(f.y);
      tile[(wq * 4 + 2) * 264 + ci] = f2bf(f.z);
      tile[(wq * 4 + 3) * 264 + ci] = f2bf(f.w);
    }
    __syncthreads();
    #pragma unroll
    for (int pass = 0; pass < 4; pass++) {
      int wl = pass * 8 + (t >> 5);
      int ci8 = (t & 31) * 8;
      short8 v = *(const short8*)&tile[wl * 264 + ci8];
      *(short8*)&xbf[(((size_t)b * HH + h) * WW + w0 + wl) * 256 + ci8] = v;
    }
  }
}

// ---------------- weight converts (BN scale folded) ----
__global__ void wcvt3_kernel(const float* __restrict__ w, const float* __restrict__ g,
                             const float* __restrict__ v, short* __restrict__ out,
                             int Cin, int CoutW, int co_off) {
  int idx = blockIdx.x * blockDim.x + threadIdx.x;
  int total = CoutW * Cin * 9;
  if (idx >= total) return;
  int t  = idx % 9;
  int ci = (idx / 9) % Cin;
  int co = idx / (9 * Cin);
  float s = g[co] * rsqrtf(v[co] + 1e-5f);
  out[((size_t)t * 256 + co_off + co) * Cin + ci] = f2bf(w[idx] * s);
}

__global__ void wcvt1_kernel(const float* __restrict__ w, const float* __restrict__ g,
                             const float* __restrict__ v, short* __restrict__ out,
                             int Cin, int CoutW) {
  int idx = blockIdx.x * blockDim.x + threadIdx.x;
  if (idx >= CoutW * Cin) return;
  int co = idx / Cin;
  float s = g[co] * rsqrtf(v[co] + 1e-5f);
  out[idx] = f2bf(w[idx] * s);
}

// ---------------- MFMA implicit-GEMM conv3x3 (+optional fused 1x1), SW-pipelined ----------------
// Block: 256 thr = 4 waves. Tile: M=128 px (one image row) x N=256 co (ALL couts).
// Wave tile: 64 px x 128 co (acc[4][8]) -> 0.366 B LDS frag traffic per KFLOP.
// K-chunks: phase A = (valid dy) x (CIN_A/32), phase B (1x1) = 8.
// Pipeline: regs hold chunk t+1's global data while MFMA consumes chunk t from LDS.
template<int CIN_A, bool PHASE_B, int SHIFT_MODE, bool SPLIT_OUT, bool OUT_F32>
__global__ __launch_bounds__(256, 2) void conv_mfma(
    const short* __restrict__ srcA, const short* __restrict__ xB,
    const short* __restrict__ wbA, const short* __restrict__ wbB,
    const float* __restrict__ g0, const float* __restrict__ b0,
    const float* __restrict__ m0, const float* __restrict__ v0,
    const float* __restrict__ g1, const float* __restrict__ b1,
    const float* __restrict__ m1, const float* __restrict__ v1,
    void* __restrict__ out0, void* __restrict__ out1)
{
  __shared__ short A_s[130 * 32];
  __shared__ short B_s[3 * 256 * 32];

  const int tid  = threadIdx.x;
  const int wave = tid >> 6;
  const int lane = tid & 63;
  const int wm = wave & 1;          // px half (64)
  const int wn = wave >> 1;         // co half (128)
  const int lr = lane & 15;
  const int lk = lane >> 4;

  const int h  = blockIdx.x & 127;
  const int b  = blockIdx.x >> 7;

  constexpr int ncA = CIN_A / 32;
  const int dystart = (h == 0) ? 1 : 0;
  const int dyend   = (h == HH - 1) ? 2 : 3;
  const int chunksA = (dyend - dystart) * ncA;
  const int total   = chunksA + (PHASE_B ? 8 : 0);

  float4v acc[4][8];
  #pragma unroll
  for (int i = 0; i < 4; i++)
    #pragma unroll
    for (int j = 0; j < 8; j++) acc[i][j] = (float4v)(0.0f);

  // pipeline registers
  short8 rA[3], rB[12];
  const short* aRow = nullptr;
  const short* bBase = nullptr;
  bool curIsA = true;

  auto decode = [&](int t, const short*& ar, const short*& bb, bool& isA) {
    isA = (t < chunksA);
    if (isA) {
      int dy  = dystart + t / ncA;
      int ci0 = (t % ncA) * 32;
      ar = srcA + (((size_t)b * HH + (h + dy - 1)) * WW) * CIN_A + ci0;
      bb = wbA + ((size_t)(dy * 3) * 256) * CIN_A + ci0;
    } else {
      int ci0 = (t - chunksA) * 32;
      ar = xB + (((size_t)b * HH + h) * WW) * 256 + ci0;
      bb = wbB + ci0;
    }
  };

  auto loadRegs = [&](const short* ar, const short* bb, bool isA) {
    if (isA) {
      #pragma unroll
      for (int i = 0; i < 2; i++) {
        int idx = tid + i * 256;
        int w = (idx >> 2) - 1, q = idx & 3;
        rA[i] = ((unsigned)w < (unsigned)WW)
                  ? *(const short8*)(ar + (size_t)w * CIN_A + q * 8) : (short8)(0);
      }
      if (tid < 8) {
        int idx = tid + 512;
        int w = (idx >> 2) - 1, q = idx & 3;
        rA[2] = ((unsigned)w < (unsigned)WW)
                  ? *(const short8*)(ar + (size_t)w * CIN_A + q * 8) : (short8)(0);
      }
      // B: 3 dx x 256 co x 4 q = 3072 granules -> 12/thread
      #pragma unroll
      for (int i = 0; i < 12; i++) {
        int idx = tid + i * 256;
        int dx = idx >> 10, rem = idx & 1023;
        int co = rem >> 2, q = rem & 3;
        rB[i] = *(const short8*)(bb + (size_t)(dx * 256 + co) * CIN_A + q * 8);
      }
    } else {
      #pragma unroll
      for (int i = 0; i < 2; i++) {
        int idx = tid + i * 256;
        int wp = idx >> 2, q = idx & 3;
        rA[i] = *(const short8*)(ar + (size_t)wp * 256 + q * 8);
      }
      // B: 256 co x 4 q = 1024 granules -> 4/thread
      #pragma unroll
      for (int i = 0; i < 4; i++) {
        int idx = tid + i * 256;
        int co = idx >> 2, q = idx & 3;
        rB[i] = *(const short8*)(bb + (size_t)co * 256 + q * 8);
      }
    }
  };

  auto storeLDS = [&](bool isA) {
    if (isA) {
      #pragma unroll
      for (int i = 0; i < 2; i++) {
        int idx = tid + i * 256;
        *(short8*)&A_s[swz(idx >> 2, idx & 3)] = rA[i];
      }
      if (tid < 8) {
        int idx = tid + 512;
        *(short8*)&A_s[swz(idx >> 2, idx & 3)] = rA[2];
      }
      #pragma unroll
      for (int i = 0; i < 12; i++) {
        int idx = tid + i * 256;
        int dx = idx >> 10, rem = idx & 1023;
        *(short8*)&B_s[swz(dx * 256 + (rem >> 2), rem & 3)] = rB[i];
      }
    } else {
      #pragma unroll
      for (int i = 0; i < 2; i++) {
        int idx = tid + i * 256;
        *(short8*)&A_s[swz(idx >> 2, idx & 3)] = rA[i];
      }
      #pragma unroll
      for (int i = 0; i < 4; i++) {
        int idx = tid + i * 256;
        *(short8*)&B_s[swz(idx >> 2, idx & 3)] = rB[i];
      }
    }
  };

  // prologue
  decode(0, aRow, bBase, curIsA);
  loadRegs(aRow, bBase, curIsA);

  for (int t = 0; t < total; t++) {
    bool isA = curIsA;
    __syncthreads();            // previous MFMA done reading LDS
    storeLDS(isA);              // waits on this chunk's global loads
    __syncthreads();
    if (t + 1 < total) {        // issue next chunk's loads; overlap with MFMA below
      decode(t + 1, aRow, bBase, curIsA);
      loadRegs(aRow, bBase, curIsA);
    }
    const int ndx = isA ? 3 : 1;
    for (int dx = 0; dx < ndx; dx++) {
      short8 af[4];
      #pragma unroll
      for (int mi = 0; mi < 4; mi++)
        af[mi] = *(const short8*)&A_s[swz(wm * 64 + mi * 16 + lr + dx, lk)];
      #pragma unroll
      for (int ni = 0; ni < 8; ni++) {
        short8 bfr = *(const short8*)&B_s[swz(dx * 256 + wn * 128 + ni * 16 + lr, lk)];
        #pragma unroll
        for (int mi = 0; mi < 4; mi++)
          acc[mi][ni] = __builtin_amdgcn_mfma_f32_16x16x32_bf16(af[mi], bfr, acc[mi][ni], 0, 0, 0);
      }
    }
  }

  // ---------- epilogue: +shift (from raw BN params), relu, store ----------
  #pragma unroll
  for (int ni = 0; ni < 8; ni++) {
    int c = wn * 128 + ni * 16 + lr;          // co 0..255
    float sh;
    if (SHIFT_MODE == 0) {
      float s = g0[c] * rsqrtf(v0[c] + 1e-5f);
      sh = b0[c] - m0[c] * s;
    } else if (SHIFT_MODE == 1) {
      int cc = c & 127;
      const float* gg = (c < 128) ? g0 : g1;
      const float* bb = (c < 128) ? b0 : b1;
      const float* mm = (c < 128) ? m0 : m1;
      const float* vv = (c < 128) ? v0 : v1;
      float s = gg[cc] * rsqrtf(vv[cc] + 1e-5f);
      sh = bb[cc] - mm[cc] * s;
    } else {
      float s0 = g0[c] * rsqrtf(v0[c] + 1e-5f);
      float s1 = g1[c] * rsqrtf(v1[c] + 1e-5f);
      sh = (b0[c] - m0[c] * s0) + (b1[c] - m1[c] * s1);
    }
    #pragma unroll
    for (int mi = 0; mi < 4; mi++) {
      int px = wm * 64 + mi * 16 + lk * 4;
      float4v v = acc[mi][ni];
      v.x = fmaxf(v.x + sh, 0.0f);
      v.y = fmaxf(v.y + sh, 0.0f);
      v.z = fmaxf(v.z + sh, 0.0f);
      v.w = fmaxf(v.w + sh, 0.0f);
      if (OUT_F32) {
        float* ob = (float*)out0;
        *(float4v*)(ob + ((size_t)b * 256 + c) * HWSZ + (size_t)h * WW + px) = v;
      } else if (SPLIT_OUT) {
        short* ob = (short*)((c < 128) ? out0 : out1);
        size_t base = (((size_t)b * HH + h) * WW + px) * 128 + (c & 127);
        ob[base      ] = f2bf(v.x);
        ob[base + 128 ] = f2bf(v.y);
        ob[base + 256 ] = f2bf(v.z);
        ob[base + 384 ] = f2bf(v.w);
      } else {
        short* ob = (short*)out0;
        size_t base = (((size_t)b * HH + h) * WW + px) * 256 + c;
        ob[base      ] = f2bf(v.x);
        ob[base + 256 ] = f2bf(v.y);
        ob[base + 512 ] = f2bf(v.z);
        ob[base + 768 ] = f2bf(v.w);
      }
    }
  }
}

// ---------------- reverse cummax over H on bf16 NHWC [b][h][w][128], in place
__global__ void colscan_kernel(unsigned* __restrict__ p) {  // uint = 2 bf16
  const int t = threadIdx.x;
  const int wl = t >> 6, cp = t & 63;
  const int w = blockIdx.x * 4 + wl;
  const int b = blockIdx.y;
  float m0 = -INFINITY, m1 = -INFINITY;
  for (int h = HH - 1; h >= 0; h--) {
    size_t idx = (((size_t)b * HH + h) * WW + w) * 64 + cp;
    unsigned u = p[idx];
    float f0 = bf2f((unsigned short)(u & 0xffff));
    float f1 = bf2f((unsigned short)(u >> 16));
    m0 = fmaxf(m0, f0);
    m1 = fmaxf(m1, f1);
    p[idx] = ((unsigned)(unsigned short)f2bf(m1) << 16) | (unsigned short)f2bf(m0);
  }
}

// ---------------- reverse cummax over W on p2 + add p1 -> p1 (bf16 NHWC C=128)
__global__ __launch_bounds__(256) void rowscan_add_kernel(
    const short* __restrict__ p2, short* __restrict__ p1) {
  __shared__ short pl[128 * 128];
  const int tid = threadIdx.x;
  const int hb = blockIdx.x;
  const int b  = blockIdx.y;
  const size_t base = (((size_t)b * HH + hb) * WW) * 128;

  #pragma unroll
  for (int i = 0; i < 8; i++) {
    int idx = tid + i * 256;          // granule of 8 shorts
    *(short8*)&pl[idx * 8] = *(const short8*)(p2 + base + (size_t)idx * 8);
  }
  __syncthreads();
  if (tid < 128) {
    float m = -INFINITY;
    for (int w = WW - 1; w >= 0; w--) {
      int a = w * 128 + tid;
      m = fmaxf(m, bf2f((unsigned short)pl[a]));
      pl[a] = (short)f2bf(m);
    }
  }
  __syncthreads();
  #pragma unroll
  for (int i = 0; i < 8; i++) {
    int idx = tid + i * 256;
    short8 sv = *(const short8*)&pl[idx * 8];
    short8 ov = *(const short8*)(p1 + base + (size_t)idx * 8);
    short8 rv;
    #pragma unroll
    for (int j = 0; j < 8; j++)
      rv[j] = f2bf(bf2f((unsigned short)sv[j]) + bf2f((unsigned short)ov[j]));
    *(short8*)(p1 + base + (size_t)idx * 8) = rv;
  }
}

extern "C" void kernel_launch(void* const* d_in, const int* in_sizes, int n_in,
                              void* d_out, int out_size, void* d_ws, size_t ws_size,
                              hipStream_t stream) {
  const float* x    = (const float*)d_in[0];
  const float* w_p1 = (const float*)d_in[1];
  const float* g_p1 = (const float*)d_in[2];
  const float* b_p1 = (const float*)d_in[3];
  const float* m_p1 = (const float*)d_in[4];
  const float* v_p1 = (const float*)d_in[5];
  const float* w_p2 = (const float*)d_in[6];
  const float* g_p2 = (const float*)d_in[7];
  const float* b_p2 = (const float*)d_in[8];
  const float* m_p2 = (const float*)d_in[9];
  const float* v_p2 = (const float*)d_in[10];
  const float* w_c1 = (const float*)d_in[11];
  const float* g_c1 = (const float*)d_in[12];
  const float* b_c1 = (const float*)d_in[13];
  const float* m_c1 = (const float*)d_in[14];
  const float* v_c1 = (const float*)d_in[15];
  const float* w_c2 = (const float*)d_in[16];
  const float* g_c2 = (const float*)d_in[17];
  const float* b_c2 = (const float*)d_in[18];
  const float* m_c2 = (const float*)d_in[19];
  const float* v_c2 = (const float*)d_in[20];
  const float* w_p3 = (const float*)d_in[21];
  const float* g_p3 = (const float*)d_in[22];
  const float* b_p3 = (const float*)d_in[23];
  const float* m_p3 = (const float*)d_in[24];
  const float* v_p3 = (const float*)d_in[25];

  char* ws = (char*)d_ws;
  // Persistent tensors — total exactly 100,663,296 B.
  short* p1  = (short*)(ws + 0);          // bf16 NHWC [4][128][128][128]  16 MB
  short* p2  = (short*)(ws + 16777216);   // bf16 NHWC [4][128][128][128]  16 MB
  short* r   = (short*)(ws + 33554432);   // bf16 NHWC [4][128][128][256]  32 MB
  short* xbf = (short*)(ws + 67108864);   // bf16 NHWC [4][128][128][256]  32 MB
  // Weight buffers overlay dead regions (stream-ordered):
  short* wb12 = r;                        // [9][256][256]; dead before c1 writes r
  short* wbc1 = p2;                       // [9][256][128]; written after rowscan_add
  short* wbc2 = (short*)(ws + 16777216 + 589824);  // [256][256], in p2 region
  short* wbp3 = p1;                       // [9][256][256]; written after c1

  // x -> NHWC bf16
  xcvt_kernel<<<dim3(128, 4), 256, 0, stream>>>(x, xbf);

  // weights for p1|p2 (into r region)
  wcvt3_kernel<<<(128 * 256 * 9 + 255) / 256, 256, 0, stream>>>(w_p1, g_p1, v_p1, wb12, 256, 128, 0);
  wcvt3_kernel<<<(128 * 256 * 9 + 255) / 256, 256, 0, stream>>>(w_p2, g_p2, v_p2, wb12, 256, 128, 128);

  // p1|p2 = relu(bn(conv3x3(x)))
  conv_mfma<256, false, 1, true, false><<<dim3(512), 256, 0, stream>>>(
      xbf, nullptr, wb12, nullptr,
      g_p1, b_p1, m_p1, v_p1, g_p2, b_p2, m_p2, v_p2, (void*)p1, (void*)p2);

  // corner pooling: cp1 in-place on p1, then s = rowscan(p2) + cp1 -> p1
  colscan_kernel<<<dim3(32, 4), 256, 0, stream>>>((unsigned*)p1);
  rowscan_add_kernel<<<dim3(128, 4), 256, 0, stream>>>(p2, p1);

  // weights for c1 (3x3) and c2 (1x1) into p2 region (p2 dead now)
  wcvt3_kernel<<<(256 * 128 * 9 + 255) / 256, 256, 0, stream>>>(w_c1, g_c1, v_c1, wbc1, 128, 256, 0);
  wcvt1_kernel<<<(256 * 256 + 255) / 256, 256, 0, stream>>>(w_c2, g_c2, v_c2, wbc2, 256, 256);

  // r = relu(bn1(conv3x3(s)) + bn2(conv1x1(x)))
  conv_mfma<128, true, 2, false, false><<<dim3(512), 256, 0, stream>>>(
      p1, xbf, wbc1, wbc2,
      g_c1, b_c1, m_c1, v_c1, g_c2, b_c2, m_c2, v_c2, (void*)r, nullptr);

  // weights for p3 into p1 region (p1 dead now)
  wcvt3_kernel<<<(256 * 256 * 9 + 255) / 256, 256, 0, stream>>>(w_p3, g_p3, v_p3, wbp3, 256, 256, 0);

  // out = relu(bn(conv3x3(r)))  — fp32 NCHW float4 stores
  conv_mfma<256, false, 0, false, true><<<dim3(512), 256, 0, stream>>>(
      r, nullptr, wbp3, nullptr,
      g_p3, b_p3, m_p3, v_p3, nullptr, nullptr, nullptr, nullptr, d_out, nullptr);
}